// Round 13
// baseline (622.783 us; speedup 1.0000x reference)
//
#include <hip/hip_runtime.h>
#include <hip/hip_bf16.h>

typedef signed char i8_t;
typedef _Float16 half_t;
typedef float v4fl __attribute__((ext_vector_type(4)));
typedef _Float16 v8h __attribute__((ext_vector_type(8)));
typedef int v4i __attribute__((ext_vector_type(4)));
typedef signed char v8c __attribute__((ext_vector_type(8)));
typedef signed char v16c __attribute__((ext_vector_type(16)));

__device__ __forceinline__ float ternqf(float w, float s) {
    float q = rintf(w / s);                 // true division: match jnp boundary
    return fminf(1.f, fmaxf(-1.f, q));
}

// async global->LDS, 16 bytes per lane. LDS dest must be wave-uniform base + lane*16.
__device__ __forceinline__ void gload16(const void* g, void* l) {
    __builtin_amdgcn_global_load_lds(
        (const __attribute__((address_space(1))) void*)g,
        (__attribute__((address_space(3))) void*)l, 16, 0, 0);
}

// ---------------- fused stage 1: per-block partial |w| sums for BOTH matrices -----
__global__ void abssum_partial2(const float* __restrict__ wup,
                                const float* __restrict__ wdn, long n,
                                float* __restrict__ part_up,
                                float* __restrict__ part_dn) {
    const int half = gridDim.x >> 1;             // 256
    const bool up = (blockIdx.x < half);
    const float* w = up ? wup : wdn;
    float* partial = up ? part_up : part_dn;
    const int bid = up ? blockIdx.x : blockIdx.x - half;
    long i0 = ((long)bid * 256 + threadIdx.x) * 8;
    long stride = (long)half * 256 * 8;
    float s = 0.f;
    for (long i = i0; i < n; i += stride) {
        v4fl a = *(const v4fl*)(w + i);
        v4fl b = *(const v4fl*)(w + i + 4);
#pragma unroll
        for (int j = 0; j < 4; ++j) s += fabsf(a[j]) + fabsf(b[j]);
    }
#pragma unroll
    for (int off = 32; off > 0; off >>= 1) s += __shfl_down(s, off, 64);
    __shared__ __align__(16) float red[4];
    if ((threadIdx.x & 63) == 0) red[threadIdx.x >> 6] = s;
    __syncthreads();
    if (threadIdx.x == 0)
        partial[bid] = (red[0] + red[1]) + (red[2] + red[3]);
}

// ---------------- stage 2: combine 256 partials per matrix, fixed order -----------
__global__ void abssum_final(const float* __restrict__ part_up,
                             const float* __restrict__ part_dn,
                             float* __restrict__ scales, float inv) {
    const int wv = threadIdx.x >> 6;
    const int l = threadIdx.x & 63;
    const float* part = wv ? part_dn : part_up;
    float s = ((part[l] + part[l + 64]) + (part[l + 128] + part[l + 192]));
#pragma unroll
    for (int off = 32; off > 0; off >>= 1) s += __shfl_down(s, off, 64);
    if (l == 0) scales[wv] = fmaxf(s * inv, 1e-5f);
}

// ---------------- fused ternary weight quant for BOTH matrices -------------------
__global__ void wquant2_kernel(const float* __restrict__ wup,
                               const float* __restrict__ wdn,
                               i8_t* __restrict__ wqu, i8_t* __restrict__ wqd,
                               const float* __restrict__ scales, int wblocks) {
    const bool up = ((int)blockIdx.x < wblocks);
    const float* w = up ? wup : wdn;
    i8_t* wq = up ? wqu : wqd;
    const float s = up ? scales[0] : scales[1];
    const int bid = up ? blockIdx.x : blockIdx.x - wblocks;
    long i = ((long)bid * 256 + threadIdx.x) * 8;
    v4fl a = *(const v4fl*)(w + i);
    v4fl b = *(const v4fl*)(w + i + 4);
    v8c o;
#pragma unroll
    for (int j = 0; j < 4; ++j) {
        o[j]     = (i8_t)(int)ternqf(a[j], s);
        o[j + 4] = (i8_t)(int)ternqf(b[j], s);
    }
    *(v8c*)(wq + i) = o;
}

// =================================================================================
// Wave-autonomous per-token quant (R8, kept): one wave owns one row in registers.
// =================================================================================
template <int W>   // row width in floats (2048 for x, 4096 for h); W % 1024 == 0
__global__ void rowquant_kernel(const float* __restrict__ src, i8_t* __restrict__ dst,
                                float* __restrict__ scale_out, int rows) {
    const int l = threadIdx.x & 63;
    const int row = blockIdx.x * 4 + (threadIdx.x >> 6);
    if (row >= rows) return;
    const int NI = W / 1024;                 // iters of 1024 floats per wave
    const float* p = src + (size_t)row * W + l * 16;
    float v[NI * 16];
#pragma unroll
    for (int it = 0; it < NI; ++it) {
#pragma unroll
        for (int c = 0; c < 4; ++c) {
            v4fl a = *(const v4fl*)(p + it * 1024 + c * 4);
#pragma unroll
            for (int e = 0; e < 4; ++e) v[it * 16 + c * 4 + e] = a[e];
        }
    }
    float amax = 0.f;
#pragma unroll
    for (int j = 0; j < NI * 16; ++j) amax = fmaxf(amax, fabsf(v[j]));
#pragma unroll
    for (int off = 32; off > 0; off >>= 1)
        amax = fmaxf(amax, __shfl_xor(amax, off, 64));   // all lanes hold row max
    const float m = fmaxf(amax, 1e-5f);
    if (l == 0) scale_out[row] = m / 127.f;
    const float sc = 127.f / m;
    i8_t* q = dst + (size_t)row * W + l * 16;
#pragma unroll
    for (int it = 0; it < NI; ++it) {
        v16c o;
#pragma unroll
        for (int j = 0; j < 16; ++j) {
            float t = rintf(v[it * 16 + j] * sc);
            o[j] = (i8_t)(int)fminf(127.f, fmaxf(-127.f, t));
        }
        *(v16c*)(q + it * 1024) = o;
    }
}

// ---------------- per-row amax of h (fallback paths only) -------------------------
template <typename T, int NV>
__global__ void hamax_kernel(const T* __restrict__ h, float* __restrict__ scale_out,
                             float* __restrict__ recip_out) {
    const int row = blockIdx.x;
    const int tid = threadIdx.x;
    const T* p = h + (size_t)row * (NV * 2048);
    float amax = 0.f;
#pragma unroll
    for (int it = 0; it < NV; ++it) {
        const T* s = p + ((size_t)it * 256 + tid) * 8;
#pragma unroll
        for (int j = 0; j < 8; ++j) amax = fmaxf(amax, fabsf((float)s[j]));
    }
#pragma unroll
    for (int off = 32; off > 0; off >>= 1) amax = fmaxf(amax, __shfl_xor(amax, off, 64));
    __shared__ __align__(16) float red[4];
    if ((tid & 63) == 0) red[tid >> 6] = amax;
    __syncthreads();
    if (tid == 0) {
        float m = fmaxf(fmaxf(red[0], red[1]), fmaxf(red[2], red[3]));
        m = fmaxf(m, 1e-5f);
        scale_out[row] = m / 127.f;
        recip_out[row] = 127.f / m;
    }
}

// =================================================================================
// 256x256 i8 GEMM, triple-buffered single-barrier (R13). BK=64, 3 bufs x
// (A 16KB + B 16KB) = 96KB. In tile t: stage t+2 into buf[(t+2)%3] at the TILE TOP
// — that buffer was last read in tile t-1, and every wave drained its t-1 reads
// (lgkm(0)) before the tile-boundary barrier, so no mid-tile barrier is needed.
// Staging hides under the whole tile, not just the tail MFMA cluster (removes R12's
// B1 serialization, the last remaining read-drain <-> stage coupling).
// 512 thr = 8 waves (2Mx4N), per-wave C = 128x64 via mfma_i32_16x16x64_i8.
// Per tile (ONE barrier): stage t+2 (4 gloads); read b[0-3]+a[0-3] (8), a[4-7] (4);
// lgkm(4)->MFMA mi0-3 (16); lgkm(0)->MFMA mi4-7 (16); vmcnt(4); barrier.
// vmcnt(4): outstanding = stage(t+1) 4 + stage(t+2) 4 -> retires t+1 (oldest),
// keeps t+2 in flight (never drain-0 mid-loop).
// Swizzle for 64B rows (R6-measured ZERO conflicts): slot ^= (row>>1)&3, applied to
// the GLOBAL source of global_load_lds and the ds_read address (both-sides rule).
// =================================================================================
__device__ __forceinline__ void stage_tile64b(const i8_t* __restrict__ g, int K,
                                              i8_t* l, int tid) {
#pragma unroll
    for (int i = 0; i < 2; ++i) {
        const int c = i * 512 + tid;            // chunk: 16B units, LDS-linear
        const int r = c >> 2;                   // tile row 0..255
        const int s = c & 3;                    // 16B slot in 64B row
        const int gc = ((s ^ ((r >> 1) & 3)) << 4);  // inverse-swizzled global col
        gload16(g + (size_t)r * K + gc, l + c * 16);
    }
}

#define SB() __builtin_amdgcn_sched_barrier(0)

template <int EPI>   // 0: out fp32 = acc*sw*rowscale; 2: h fp32 = relu(...)^2
__launch_bounds__(512, 2)
__global__ void gemm_bt8(const i8_t* __restrict__ A, const i8_t* __restrict__ B,
                         void* __restrict__ Cv,
                         const float* __restrict__ rowscale,
                         const float* __restrict__ wscale,
                         int M, int N, int K) {
    __shared__ __align__(16) i8_t smem[98304];   // 3 bufs x [A 16KB | B 16KB]

    const int tid = threadIdx.x;

    // XCD-aware bijective swizzle (grids here are multiples of 8)
    const int gx = gridDim.x;
    const int nwg = gx * gridDim.y;
    int flat = blockIdx.y * gx + blockIdx.x;
    if ((nwg & 7) == 0) flat = (flat & 7) * (nwg >> 3) + (flat >> 3);
    const int n0 = (flat % gx) * 256;
    const int m0 = (flat / gx) * 256;

    const i8_t* gA = A + (size_t)m0 * K;
    const i8_t* gB = B + (size_t)n0 * K;

    const int w = tid >> 6, l = tid & 63;
    const int wr = w >> 2, wc = w & 3;           // wave tile: rows wr*128, cols wc*64
    const int lrow = l & 15, lq = l >> 4;        // 16x16 frag: row lrow, k-slot lq
    const int koff = ((lq ^ ((lrow >> 1) & 3)) << 4);   // swizzled 16B slot (uniform)
    const int aBase = ((wr * 128 + lrow) << 6) + koff;  // row*64B
    const int bBase = ((wc * 64 + lrow) << 6) + koff;

    v4i acc[8][4];
#pragma unroll
    for (int a = 0; a < 8; ++a)
#pragma unroll
        for (int b = 0; b < 4; ++b) acc[a][b] = (v4i){0, 0, 0, 0};

    const int NT = K >> 6;
    // prologue: stage tiles 0,1 (4 loads each); t0 resident, t1 in flight
    stage_tile64b(gB, K, smem + 16384, tid);
    stage_tile64b(gA, K, smem, tid);
    stage_tile64b(gB + 64, K, smem + 32768 + 16384, tid);
    stage_tile64b(gA + 64, K, smem + 32768, tid);
    asm volatile("s_waitcnt vmcnt(4)" ::: "memory");
    __builtin_amdgcn_s_barrier();
    SB();

    int cur = 0;                                 // t % 3
    for (int t = 0; t < NT; ++t) {
        i8_t* Ab = smem + cur * 32768;
        i8_t* Bb = Ab + 16384;
        const bool pf = (t + 2 < NT);

        // ---- stage t+2 into buf[(t+2)%3] (last read in tile t-1; safe: every
        //      wave drained its t-1 reads before the tile-boundary barrier) ----
        if (pf) {
            int s2 = cur + 2; if (s2 >= 3) s2 -= 3;
            i8_t* Sb = smem + s2 * 32768;
            stage_tile64b(gB + (size_t)(t + 2) * 64, K, Sb + 16384, tid);
            stage_tile64b(gA + (size_t)(t + 2) * 64, K, Sb, tid);
        }
        SB();

        v4i a0[4], a1[4], b0[4];
        // ---- reads: b[0-3] + a[0-3] (8), then a[4-7] (4) ----
#pragma unroll
        for (int nj = 0; nj < 4; ++nj)
            b0[nj] = *(const v4i*)(Bb + bBase + (nj << 10));
#pragma unroll
        for (int mi = 0; mi < 4; ++mi)
            a0[mi] = *(const v4i*)(Ab + aBase + (mi << 10));
        SB();
#pragma unroll
        for (int mi = 0; mi < 4; ++mi)
            a1[mi] = *(const v4i*)(Ab + aBase + ((mi + 4) << 10));
        SB();
        asm volatile("s_waitcnt lgkmcnt(4)" ::: "memory");   // b0 + a0 retired
        SB();
        __builtin_amdgcn_s_setprio(1);
#pragma unroll
        for (int mi = 0; mi < 4; ++mi)
#pragma unroll
            for (int nj = 0; nj < 4; ++nj)
                acc[mi][nj] = __builtin_amdgcn_mfma_i32_16x16x64_i8(
                    a0[mi], b0[nj], acc[mi][nj], 0, 0, 0);
        __builtin_amdgcn_s_setprio(0);
        SB();
        asm volatile("s_waitcnt lgkmcnt(0)" ::: "memory");   // a1 retired
        SB();
        __builtin_amdgcn_s_setprio(1);
#pragma unroll
        for (int mi = 0; mi < 4; ++mi)
#pragma unroll
            for (int nj = 0; nj < 4; ++nj)
                acc[mi + 4][nj] = __builtin_amdgcn_mfma_i32_16x16x64_i8(
                    a1[mi], b0[nj], acc[mi + 4][nj], 0, 0, 0);
        __builtin_amdgcn_s_setprio(0);
        SB();
        // tile end: retire t+1's staged loads, keep t+2's 4 in flight
        if (pf) {
            asm volatile("s_waitcnt vmcnt(4)" ::: "memory");
        } else if (t + 1 < NT) {
            asm volatile("s_waitcnt vmcnt(0)" ::: "memory");
        }
        if (t + 1 < NT) {
            __builtin_amdgcn_s_barrier();    // buf t+1 fully written for all waves
            SB();
        }
        ++cur; if (cur == 3) cur = 0;
    }

    // epilogue: 16x16 C/D layout: col = lane&15, row = (lane>>4)*4 + reg
    const float sw = wscale[0];   // pre-clipped mean|w|
#pragma unroll
    for (int mi = 0; mi < 8; ++mi) {
#pragma unroll
        for (int r = 0; r < 4; ++r) {
            const int row = m0 + wr * 128 + mi * 16 + lq * 4 + r;
            const float rs = sw * rowscale[row];
#pragma unroll
            for (int nj = 0; nj < 4; ++nj) {
                const int col = n0 + wc * 64 + nj * 16 + lrow;
                float v = (float)acc[mi][nj][r] * rs;   // exact: |acc| < 2^24
                if (EPI == 0) {
                    ((float*)Cv)[(size_t)row * N + col] = v;
                } else {
                    v = fmaxf(v, 0.f); v = v * v;
                    ((float*)Cv)[(size_t)row * N + col] = v;
                }
            }
        }
    }
}

// ---------------- 128x128 m97-structure i8 GEMM (fallback paths) ------------------
template <int ASRC, int EPI>
__launch_bounds__(256, 2)
__global__ void gemm_bt(const void* __restrict__ Av, const i8_t* __restrict__ B,
                        void* __restrict__ Cv,
                        const float* __restrict__ rowscale,
                        const float* __restrict__ arecip,
                        const float* __restrict__ wscale,
                        int M, int N, int K) {
    __shared__ __align__(16) i8_t As[128 * 64];
    __shared__ __align__(16) i8_t Bs[128 * 64];

    const int tid = threadIdx.x;
    const int gx = gridDim.x;
    const int nwg = gx * gridDim.y;
    int flat = blockIdx.y * gx + blockIdx.x;
    if ((nwg & 7) == 0) flat = (flat & 7) * (nwg >> 3) + (flat >> 3);
    const int n0 = (flat % gx) * 128;
    const int m0 = (flat / gx) * 128;

    const int srow = tid >> 2;
    const int scol = (tid & 3) * 16;
    const i8_t* gB0 = B + (size_t)(n0 + srow) * K + scol;
    const i8_t* gB1 = B + (size_t)(n0 + 64 + srow) * K + scol;
    i8_t* lB0 = Bs + tid * 16;
    i8_t* lB1 = Bs + 4096 + tid * 16;

    const i8_t* gA0 = nullptr;
    const i8_t* gA1 = nullptr;
    i8_t* lA0 = As + tid * 16;
    i8_t* lA1 = As + 4096 + tid * 16;
    if (ASRC == 0) {
        gA0 = (const i8_t*)Av + (size_t)(m0 + srow) * K + scol;
        gA1 = (const i8_t*)Av + (size_t)(m0 + 64 + srow) * K + scol;
    }

    const int qrow = tid >> 1;
    const int qcol = (tid & 1) * 32;
    const float* gA32 = (const float*)Av + (size_t)(m0 + qrow) * K + qcol;
    const half_t* gAh = (const half_t*)Av + (size_t)(m0 + qrow) * K + qcol;
    i8_t* qdst = As + qrow * 64 + qcol;
    const float qsc = (ASRC != 0) ? arecip[m0 + qrow] : 0.f;

    const int w = tid >> 6, l = tid & 63;
    const int wr = w >> 1, wc = w & 1;
    const int lrow = l & 15, lq = l >> 4;

    v4i acc[4][4];
#pragma unroll
    for (int a = 0; a < 4; ++a)
#pragma unroll
        for (int b = 0; b < 4; ++b) acc[a][b] = (v4i){0, 0, 0, 0};

    const int kiters = K / 64;
    for (int kt = 0; kt < kiters; ++kt) {
        const int off = kt * 64;
        v16c r0, r1;
        if (ASRC == 1) {
#pragma unroll
            for (int c = 0; c < 4; ++c) {
                v4fl f0 = *(const v4fl*)(gA32 + off + c * 4);
                v4fl f1 = *(const v4fl*)(gA32 + off + 16 + c * 4);
#pragma unroll
                for (int e = 0; e < 4; ++e) {
                    float t0 = rintf(f0[e] * qsc);
                    float t1 = rintf(f1[e] * qsc);
                    r0[c * 4 + e] = (i8_t)(int)fminf(127.f, fmaxf(-127.f, t0));
                    r1[c * 4 + e] = (i8_t)(int)fminf(127.f, fmaxf(-127.f, t1));
                }
            }
        } else if (ASRC == 2) {
#pragma unroll
            for (int c = 0; c < 2; ++c) {
                v8h h0 = *(const v8h*)(gAh + off + c * 8);
                v8h h1 = *(const v8h*)(gAh + off + 16 + c * 8);
#pragma unroll
                for (int e = 0; e < 8; ++e) {
                    float t0 = rintf((float)h0[e] * qsc);
                    float t1 = rintf((float)h1[e] * qsc);
                    r0[c * 8 + e] = (i8_t)(int)fminf(127.f, fmaxf(-127.f, t0));
                    r1[c * 8 + e] = (i8_t)(int)fminf(127.f, fmaxf(-127.f, t1));
                }
            }
        }
        __syncthreads();
        gload16(gB0 + off, lB0);
        gload16(gB1 + off, lB1);
        if (ASRC == 0) {
            gload16(gA0 + off, lA0);
            gload16(gA1 + off, lA1);
        } else {
            *(v16c*)qdst = r0;
            *(v16c*)(qdst + 16) = r1;
        }
        __syncthreads();

        v4i af[4], bfr[4];
#pragma unroll
        for (int mi = 0; mi < 4; ++mi)
            af[mi] = *(const v4i*)(As + (wr * 64 + mi * 16 + lrow) * 64 + lq * 16);
#pragma unroll
        for (int nj = 0; nj < 4; ++nj)
            bfr[nj] = *(const v4i*)(Bs + (wc * 64 + nj * 16 + lrow) * 64 + lq * 16);
#pragma unroll
        for (int mi = 0; mi < 4; ++mi)
#pragma unroll
            for (int nj = 0; nj < 4; ++nj)
                acc[mi][nj] = __builtin_amdgcn_mfma_i32_16x16x64_i8(
                    af[mi], bfr[nj], acc[mi][nj], 0, 0, 0);
    }

    const float sw = wscale[0];
#pragma unroll
    for (int mi = 0; mi < 4; ++mi) {
#pragma unroll
        for (int r = 0; r < 4; ++r) {
            const int row = m0 + wr * 64 + mi * 16 + lq * 4 + r;
            const float rs = sw * rowscale[row];
#pragma unroll
            for (int nj = 0; nj < 4; ++nj) {
                const int col = n0 + wc * 64 + nj * 16 + lrow;
                float v = (float)acc[mi][nj][r] * rs;
                if (EPI == 0) {
                    ((float*)Cv)[(size_t)row * N + col] = v;
                } else if (EPI == 1) {
                    v = fmaxf(v, 0.f); v = v * v;
                    ((half_t*)Cv)[(size_t)row * N + col] = (half_t)v;
                } else {
                    v = fmaxf(v, 0.f); v = v * v;
                    ((float*)Cv)[(size_t)row * N + col] = v;
                }
            }
        }
    }
}

extern "C" void kernel_launch(void* const* d_in, const int* in_sizes, int n_in,
                              void* d_out, int out_size, void* d_ws, size_t ws_size,
                              hipStream_t stream) {
    const float* x   = (const float*)d_in[0];   // [T, H] fp32
    const float* wup = (const float*)d_in[1];   // [I, H] fp32
    const float* wdn = (const float*)d_in[2];   // [H, I] fp32

    const int H = 2048;
    const int T = in_sizes[0] / H;              // 16384
    const int I = in_sizes[1] / H;              // 4096
    const long nw = (long)in_sizes[1];          // 8388608
    const float winv = 1.0f / (float)nw;

    char* p = (char*)d_ws;
    float* scales  = (float*)p;
    float* part_up = (float*)(p + 256);
    float* part_dn = (float*)(p + 1280);
    float* a_scale = (float*)(p + 2304);
    float* h_scale = a_scale + T;
    float* h_recip = h_scale + T;
    size_t off = 2304 + (size_t)12 * T;
    off = (off + 255) & ~(size_t)255;
    i8_t* xq  = (i8_t*)(p + off); off += (size_t)T * H;
    off = (off + 255) & ~(size_t)255;
    i8_t* wqu = (i8_t*)(p + off); off += (size_t)I * H;
    off = (off + 255) & ~(size_t)255;
    i8_t* wqd = (i8_t*)(p + off); off += (size_t)H * I;
    off = (off + 255) & ~(size_t)255;
    void* h  = (void*)(p + off);
    i8_t* hq = (i8_t*)(p + off + (size_t)T * I * 4);

    const size_t need_full = off + (size_t)T * I * 5;
    const size_t need_h32  = off + (size_t)T * I * 4;
    const int mode = (ws_size == 0 || need_full <= ws_size) ? 0
                   : (need_h32 <= ws_size ? 1 : 2);
    const bool big_ok = (T % 256 == 0) && (I % 256 == 0) && (H % 256 == 0) &&
                        (H >= 256) && (I >= 256);

    // fused deterministic mean|w| for both matrices, then fixed-order combine
    abssum_partial2<<<512, 256, 0, stream>>>(wup, wdn, nw, part_up, part_dn);
    abssum_final<<<1, 128, 0, stream>>>(part_up, part_dn, scales, winv);

    int wblocks = (int)(nw / 2048);
    wquant2_kernel<<<2 * wblocks, 256, 0, stream>>>(wup, wdn, wqu, wqd, scales, wblocks);

    rowquant_kernel<2048><<<(T + 3) / 4, 256, 0, stream>>>(x, xq, a_scale, T);

    if (mode == 0 && big_ok) {
        gemm_bt8<2><<<dim3(I / 256, T / 256), 512, 0, stream>>>(
            xq, wqu, h, a_scale, scales + 0, T, I, H);
        rowquant_kernel<4096><<<(T + 3) / 4, 256, 0, stream>>>(
            (const float*)h, hq, h_scale, T);
        gemm_bt8<0><<<dim3(H / 256, T / 256), 512, 0, stream>>>(
            hq, wqd, d_out, h_scale, scales + 1, T, H, I);
    } else if (mode == 0) {
        gemm_bt<0, 2><<<dim3(I / 128, T / 128), 256, 0, stream>>>(
            xq, wqu, h, a_scale, nullptr, scales + 0, T, I, H);
        rowquant_kernel<4096><<<(T + 3) / 4, 256, 0, stream>>>(
            (const float*)h, hq, h_scale, T);
        gemm_bt<0, 0><<<dim3(H / 128, T / 128), 256, 0, stream>>>(
            hq, wqd, d_out, h_scale, nullptr, scales + 1, T, H, I);
    } else if (mode == 1) {
        gemm_bt<0, 2><<<dim3(I / 128, T / 128), 256, 0, stream>>>(
            xq, wqu, h, a_scale, nullptr, scales + 0, T, I, H);
        hamax_kernel<float, 2><<<T, 256, 0, stream>>>((const float*)h, h_scale, h_recip);
        gemm_bt<1, 0><<<dim3(H / 128, T / 128), 256, 0, stream>>>(
            h, wqd, d_out, h_scale, h_recip, scales + 1, T, H, I);
    } else {
        gemm_bt<0, 1><<<dim3(I / 128, T / 128), 256, 0, stream>>>(
            xq, wqu, h, a_scale, nullptr, scales + 0, T, I, H);
        hamax_kernel<half_t, 2><<<T, 256, 0, stream>>>((const half_t*)h, h_scale, h_recip);
        gemm_bt<2, 0><<<dim3(H / 128, T / 128), 256, 0, stream>>>(
            h, wqd, d_out, h_scale, h_recip, scales + 1, T, H, I);
    }
}

// Round 14
// 612.624 us; speedup vs baseline: 1.0166x; 1.0166x over previous
//
#include <hip/hip_runtime.h>
#include <hip/hip_bf16.h>

typedef signed char i8_t;
typedef _Float16 half_t;
typedef float v4fl __attribute__((ext_vector_type(4)));
typedef _Float16 v8h __attribute__((ext_vector_type(8)));
typedef int v4i __attribute__((ext_vector_type(4)));
typedef signed char v8c __attribute__((ext_vector_type(8)));
typedef signed char v16c __attribute__((ext_vector_type(16)));

__device__ __forceinline__ float ternqf(float w, float s) {
    float q = rintf(w / s);                 // true division: match jnp boundary
    return fminf(1.f, fmaxf(-1.f, q));
}

// async global->LDS, 16 bytes per lane. LDS dest must be wave-uniform base + lane*16.
__device__ __forceinline__ void gload16(const void* g, void* l) {
    __builtin_amdgcn_global_load_lds(
        (const __attribute__((address_space(1))) void*)g,
        (__attribute__((address_space(3))) void*)l, 16, 0, 0);
}

// ---------------- fused stage 1: per-block partial |w| sums for BOTH matrices -----
__global__ void abssum_partial2(const float* __restrict__ wup,
                                const float* __restrict__ wdn, long n,
                                float* __restrict__ part_up,
                                float* __restrict__ part_dn) {
    const int half = gridDim.x >> 1;             // 256
    const bool up = (blockIdx.x < half);
    const float* w = up ? wup : wdn;
    float* partial = up ? part_up : part_dn;
    const int bid = up ? blockIdx.x : blockIdx.x - half;
    long i0 = ((long)bid * 256 + threadIdx.x) * 8;
    long stride = (long)half * 256 * 8;
    float s = 0.f;
    for (long i = i0; i < n; i += stride) {
        v4fl a = *(const v4fl*)(w + i);
        v4fl b = *(const v4fl*)(w + i + 4);
#pragma unroll
        for (int j = 0; j < 4; ++j) s += fabsf(a[j]) + fabsf(b[j]);
    }
#pragma unroll
    for (int off = 32; off > 0; off >>= 1) s += __shfl_down(s, off, 64);
    __shared__ __align__(16) float red[4];
    if ((threadIdx.x & 63) == 0) red[threadIdx.x >> 6] = s;
    __syncthreads();
    if (threadIdx.x == 0)
        partial[bid] = (red[0] + red[1]) + (red[2] + red[3]);
}

// ---------------- stage 2: combine 256 partials per matrix, fixed order -----------
__global__ void abssum_final(const float* __restrict__ part_up,
                             const float* __restrict__ part_dn,
                             float* __restrict__ scales, float inv) {
    const int wv = threadIdx.x >> 6;
    const int l = threadIdx.x & 63;
    const float* part = wv ? part_dn : part_up;
    float s = ((part[l] + part[l + 64]) + (part[l + 128] + part[l + 192]));
#pragma unroll
    for (int off = 32; off > 0; off >>= 1) s += __shfl_down(s, off, 64);
    if (l == 0) scales[wv] = fmaxf(s * inv, 1e-5f);
}

// ---------------- fused ternary weight quant for BOTH matrices -------------------
__global__ void wquant2_kernel(const float* __restrict__ wup,
                               const float* __restrict__ wdn,
                               i8_t* __restrict__ wqu, i8_t* __restrict__ wqd,
                               const float* __restrict__ scales, int wblocks) {
    const bool up = ((int)blockIdx.x < wblocks);
    const float* w = up ? wup : wdn;
    i8_t* wq = up ? wqu : wqd;
    const float s = up ? scales[0] : scales[1];
    const int bid = up ? blockIdx.x : blockIdx.x - wblocks;
    long i = ((long)bid * 256 + threadIdx.x) * 8;
    v4fl a = *(const v4fl*)(w + i);
    v4fl b = *(const v4fl*)(w + i + 4);
    v8c o;
#pragma unroll
    for (int j = 0; j < 4; ++j) {
        o[j]     = (i8_t)(int)ternqf(a[j], s);
        o[j + 4] = (i8_t)(int)ternqf(b[j], s);
    }
    *(v8c*)(wq + i) = o;
}

// =================================================================================
// Wave-autonomous per-token quant (R8, kept): one wave owns one row in registers.
// =================================================================================
template <int W>   // row width in floats (2048 for x, 4096 for h); W % 1024 == 0
__global__ void rowquant_kernel(const float* __restrict__ src, i8_t* __restrict__ dst,
                                float* __restrict__ scale_out, int rows) {
    const int l = threadIdx.x & 63;
    const int row = blockIdx.x * 4 + (threadIdx.x >> 6);
    if (row >= rows) return;
    const int NI = W / 1024;                 // iters of 1024 floats per wave
    const float* p = src + (size_t)row * W + l * 16;
    float v[NI * 16];
#pragma unroll
    for (int it = 0; it < NI; ++it) {
#pragma unroll
        for (int c = 0; c < 4; ++c) {
            v4fl a = *(const v4fl*)(p + it * 1024 + c * 4);
#pragma unroll
            for (int e = 0; e < 4; ++e) v[it * 16 + c * 4 + e] = a[e];
        }
    }
    float amax = 0.f;
#pragma unroll
    for (int j = 0; j < NI * 16; ++j) amax = fmaxf(amax, fabsf(v[j]));
#pragma unroll
    for (int off = 32; off > 0; off >>= 1)
        amax = fmaxf(amax, __shfl_xor(amax, off, 64));   // all lanes hold row max
    const float m = fmaxf(amax, 1e-5f);
    if (l == 0) scale_out[row] = m / 127.f;
    const float sc = 127.f / m;
    i8_t* q = dst + (size_t)row * W + l * 16;
#pragma unroll
    for (int it = 0; it < NI; ++it) {
        v16c o;
#pragma unroll
        for (int j = 0; j < 16; ++j) {
            float t = rintf(v[it * 16 + j] * sc);
            o[j] = (i8_t)(int)fminf(127.f, fmaxf(-127.f, t));
        }
        *(v16c*)(q + it * 1024) = o;
    }
}

// ---------------- per-row amax of h (fallback paths only) -------------------------
template <typename T, int NV>
__global__ void hamax_kernel(const T* __restrict__ h, float* __restrict__ scale_out,
                             float* __restrict__ recip_out) {
    const int row = blockIdx.x;
    const int tid = threadIdx.x;
    const T* p = h + (size_t)row * (NV * 2048);
    float amax = 0.f;
#pragma unroll
    for (int it = 0; it < NV; ++it) {
        const T* s = p + ((size_t)it * 256 + tid) * 8;
#pragma unroll
        for (int j = 0; j < 8; ++j) amax = fmaxf(amax, fabsf((float)s[j]));
    }
#pragma unroll
    for (int off = 32; off > 0; off >>= 1) amax = fmaxf(amax, __shfl_xor(amax, off, 64));
    __shared__ __align__(16) float red[4];
    if ((tid & 63) == 0) red[tid >> 6] = amax;
    __syncthreads();
    if (tid == 0) {
        float m = fmaxf(fmaxf(red[0], red[1]), fmaxf(red[2], red[3]));
        m = fmaxf(m, 1e-5f);
        scale_out[row] = m / 127.f;
        recip_out[row] = 127.f / m;
    }
}

// =================================================================================
// 256x256 i8 GEMM, counted-wait + staging hoist (R12 — session-best, FINAL).
// Schedule-space summary (this session): lockstep 4-phase (R3) 182us; 32x32 (R5)
// 195us; 16-wave occupancy-first (R6) 183us; pipe-balanced lockstep (R7) 177us;
// B-in-registers (R9) 245us; counted-lgkm waits (R11) 162us (+9% — barriers WERE
// serializing LDS vs MFMA); staging hoist (R12) 160us; triple-buffer BK=64 (R13)
// 169us (worse amortization). R12 held as best.
//   tile: g1(8 reads); g2(8); lgkm(8)->MFMA1; g3(4); lgkm(4)->MFMA2; g4(4);
//         lgkm(0); B1; stage t+2; MFMA3+MFMA4 (32 contiguous); vmcnt(8); B2
// B1 = lgkm(0)+barrier: all waves' buf-t reads drained before staging overwrites.
// B2 = vmcnt(8)+barrier: buf t+1 fully written; t+2's 8 loads stay in flight
// (never drain-0 mid-loop). sched_barrier(0) pins every region (rule 18).
// =================================================================================
__device__ __forceinline__ void stage_tile256(const i8_t* __restrict__ g, int K,
                                              i8_t* l, int tid) {
#pragma unroll
    for (int i = 0; i < 4; ++i) {
        const int c = i * 512 + tid;            // chunk: 16B units, LDS-linear
        const int r = c >> 3;                   // tile row 0..255
        const int lc = (((c & 7) ^ (r & 7)) << 4);  // inverse-swizzled global col
        gload16(g + (size_t)r * K + lc, l + c * 16);
    }
}

#define SB() __builtin_amdgcn_sched_barrier(0)

template <int EPI>   // 0: out fp32 = acc*sw*rowscale; 2: h fp32 = relu(...)^2
__launch_bounds__(512, 2)
__global__ void gemm_bt8(const i8_t* __restrict__ A, const i8_t* __restrict__ B,
                         void* __restrict__ Cv,
                         const float* __restrict__ rowscale,
                         const float* __restrict__ wscale,
                         int M, int N, int K) {
    __shared__ __align__(16) i8_t smem[131072];   // [2 buf][ A 32KB | B 32KB ]

    const int tid = threadIdx.x;

    // XCD-aware bijective swizzle (grids here are multiples of 8)
    const int gx = gridDim.x;
    const int nwg = gx * gridDim.y;
    int flat = blockIdx.y * gx + blockIdx.x;
    if ((nwg & 7) == 0) flat = (flat & 7) * (nwg >> 3) + (flat >> 3);
    const int n0 = (flat % gx) * 256;
    const int m0 = (flat / gx) * 256;

    const i8_t* gA = A + (size_t)m0 * K;
    const i8_t* gB = B + (size_t)n0 * K;

    const int w = tid >> 6, l = tid & 63;
    const int wr = w >> 2, wc = w & 3;           // wave tile: rows wr*128, cols wc*64
    const int lrow = l & 15, lq = l >> 4;        // 16x16 frag: row lrow, k-slot lq
    const int lr7 = lrow & 7;
    const int kk0 = ((lq)     ^ lr7) << 4;       // swizzled 16B slot, ks0 (slots 0-3)
    const int kk1 = ((lq + 4) ^ lr7) << 4;       // ks1 (slots 4-7)
    const int aBase = ((wr * 128 + lrow) << 7);  // row * 128B
    const int bBase = ((wc * 64 + lrow) << 7);

    v4i acc[8][4];
#pragma unroll
    for (int a = 0; a < 8; ++a)
#pragma unroll
        for (int b = 0; b < 4; ++b) acc[a][b] = (v4i){0, 0, 0, 0};

    const int NT = K >> 7;
    // prologue: tiles 0 and 1 (B then A each; oldest 8 outstanding = tile0)
    stage_tile256(gB, K, smem + 32768, tid);
    stage_tile256(gA, K, smem, tid);
    stage_tile256(gB + 128, K, smem + 65536 + 32768, tid);
    stage_tile256(gA + 128, K, smem + 65536, tid);
    asm volatile("s_waitcnt vmcnt(8)" ::: "memory");   // tile0 resident; tile1 in flight
    __builtin_amdgcn_s_barrier();
    SB();

    for (int t = 0; t < NT; ++t) {
        i8_t* Ab = smem + ((t & 1) << 16);
        i8_t* Bb = Ab + 32768;
        const bool pf = (t + 2 < NT);

        v4i a0[4], a1[4], b0[4], b1[4];

        // ---- g1: b0 + A[0-3].ks0 (8 reads) ----
#pragma unroll
        for (int nj = 0; nj < 4; ++nj)
            b0[nj] = *(const v4i*)(Bb + bBase + (nj << 11) + kk0);
#pragma unroll
        for (int mi = 0; mi < 4; ++mi)
            a0[mi] = *(const v4i*)(Ab + aBase + (mi << 11) + kk0);
        SB();
        // ---- g2: b1 + A[4-7].ks0 (8 reads) ----
#pragma unroll
        for (int nj = 0; nj < 4; ++nj)
            b1[nj] = *(const v4i*)(Bb + bBase + (nj << 11) + kk1);
#pragma unroll
        for (int mi = 0; mi < 4; ++mi)
            a1[mi] = *(const v4i*)(Ab + aBase + ((mi + 4) << 11) + kk0);
        SB();
        asm volatile("s_waitcnt lgkmcnt(8)" ::: "memory");   // g1 retired
        SB();
        __builtin_amdgcn_s_setprio(1);
#pragma unroll
        for (int mi = 0; mi < 4; ++mi)
#pragma unroll
            for (int nj = 0; nj < 4; ++nj)
                acc[mi][nj] = __builtin_amdgcn_mfma_i32_16x16x64_i8(
                    a0[mi], b0[nj], acc[mi][nj], 0, 0, 0);
        __builtin_amdgcn_s_setprio(0);
        SB();
        // ---- g3: A[0-3].ks1 -> a0 (4 reads; a0 consumed by MFMA1) ----
#pragma unroll
        for (int mi = 0; mi < 4; ++mi)
            a0[mi] = *(const v4i*)(Ab + aBase + (mi << 11) + kk1);
        SB();
        asm volatile("s_waitcnt lgkmcnt(4)" ::: "memory");   // g2 retired (g3 outstanding)
        SB();
        __builtin_amdgcn_s_setprio(1);
#pragma unroll
        for (int mi = 0; mi < 4; ++mi)
#pragma unroll
            for (int nj = 0; nj < 4; ++nj)
                acc[mi + 4][nj] = __builtin_amdgcn_mfma_i32_16x16x64_i8(
                    a1[mi], b0[nj], acc[mi + 4][nj], 0, 0, 0);
        __builtin_amdgcn_s_setprio(0);
        SB();
        // ---- g4: A[4-7].ks1 -> a1 (4 reads; a1 consumed by MFMA2) ----
#pragma unroll
        for (int mi = 0; mi < 4; ++mi)
            a1[mi] = *(const v4i*)(Ab + aBase + ((mi + 4) << 11) + kk1);
        SB();
        asm volatile("s_waitcnt lgkmcnt(0)" ::: "memory");   // g3+g4 retired: ALL reads done
        SB();
        __builtin_amdgcn_s_barrier();        // B1: every wave's reads of buf t drained
        SB();
        // ---- stage t+2 into this buffer (hoisted: hides under MFMA3+MFMA4) ----
        if (pf) {
            stage_tile256(gB + (size_t)(t + 2) * 128, K, Bb, tid);
            stage_tile256(gA + (size_t)(t + 2) * 128, K, Ab, tid);
        }
        SB();
        __builtin_amdgcn_s_setprio(1);
#pragma unroll
        for (int mi = 0; mi < 4; ++mi)
#pragma unroll
            for (int nj = 0; nj < 4; ++nj)
                acc[mi][nj] = __builtin_amdgcn_mfma_i32_16x16x64_i8(
                    a0[mi], b1[nj], acc[mi][nj], 0, 0, 0);
#pragma unroll
        for (int mi = 0; mi < 4; ++mi)
#pragma unroll
            for (int nj = 0; nj < 4; ++nj)
                acc[mi + 4][nj] = __builtin_amdgcn_mfma_i32_16x16x64_i8(
                    a1[mi], b1[nj], acc[mi + 4][nj], 0, 0, 0);
        __builtin_amdgcn_s_setprio(0);
        SB();
        // tile end: retire tile t+1's loads, keep t+2's 8 in flight (never drain-0)
        if (pf) {
            asm volatile("s_waitcnt vmcnt(8)" ::: "memory");
        } else if (t + 1 < NT) {
            asm volatile("s_waitcnt vmcnt(0)" ::: "memory");
        }
        if (t + 1 < NT) {
            __builtin_amdgcn_s_barrier();    // B2: buf t+1 fully written for all waves
            SB();
        }
    }

    // epilogue: 16x16 C/D layout: col = lane&15, row = (lane>>4)*4 + reg
    const float sw = wscale[0];   // pre-clipped mean|w|
#pragma unroll
    for (int mi = 0; mi < 8; ++mi) {
#pragma unroll
        for (int r = 0; r < 4; ++r) {
            const int row = m0 + wr * 128 + mi * 16 + lq * 4 + r;
            const float rs = sw * rowscale[row];
#pragma unroll
            for (int nj = 0; nj < 4; ++nj) {
                const int col = n0 + wc * 64 + nj * 16 + lrow;
                float v = (float)acc[mi][nj][r] * rs;   // exact: |acc| < 2^24
                if (EPI == 0) {
                    ((float*)Cv)[(size_t)row * N + col] = v;
                } else {
                    v = fmaxf(v, 0.f); v = v * v;
                    ((float*)Cv)[(size_t)row * N + col] = v;
                }
            }
        }
    }
}

// ---------------- 128x128 m97-structure i8 GEMM (fallback paths) ------------------
template <int ASRC, int EPI>
__launch_bounds__(256, 2)
__global__ void gemm_bt(const void* __restrict__ Av, const i8_t* __restrict__ B,
                        void* __restrict__ Cv,
                        const float* __restrict__ rowscale,
                        const float* __restrict__ arecip,
                        const float* __restrict__ wscale,
                        int M, int N, int K) {
    __shared__ __align__(16) i8_t As[128 * 64];
    __shared__ __align__(16) i8_t Bs[128 * 64];

    const int tid = threadIdx.x;
    const int gx = gridDim.x;
    const int nwg = gx * gridDim.y;
    int flat = blockIdx.y * gx + blockIdx.x;
    if ((nwg & 7) == 0) flat = (flat & 7) * (nwg >> 3) + (flat >> 3);
    const int n0 = (flat % gx) * 128;
    const int m0 = (flat / gx) * 128;

    const int srow = tid >> 2;
    const int scol = (tid & 3) * 16;
    const i8_t* gB0 = B + (size_t)(n0 + srow) * K + scol;
    const i8_t* gB1 = B + (size_t)(n0 + 64 + srow) * K + scol;
    i8_t* lB0 = Bs + tid * 16;
    i8_t* lB1 = Bs + 4096 + tid * 16;

    const i8_t* gA0 = nullptr;
    const i8_t* gA1 = nullptr;
    i8_t* lA0 = As + tid * 16;
    i8_t* lA1 = As + 4096 + tid * 16;
    if (ASRC == 0) {
        gA0 = (const i8_t*)Av + (size_t)(m0 + srow) * K + scol;
        gA1 = (const i8_t*)Av + (size_t)(m0 + 64 + srow) * K + scol;
    }

    const int qrow = tid >> 1;
    const int qcol = (tid & 1) * 32;
    const float* gA32 = (const float*)Av + (size_t)(m0 + qrow) * K + qcol;
    const half_t* gAh = (const half_t*)Av + (size_t)(m0 + qrow) * K + qcol;
    i8_t* qdst = As + qrow * 64 + qcol;
    const float qsc = (ASRC != 0) ? arecip[m0 + qrow] : 0.f;

    const int w = tid >> 6, l = tid & 63;
    const int wr = w >> 1, wc = w & 1;
    const int lrow = l & 15, lq = l >> 4;

    v4i acc[4][4];
#pragma unroll
    for (int a = 0; a < 4; ++a)
#pragma unroll
        for (int b = 0; b < 4; ++b) acc[a][b] = (v4i){0, 0, 0, 0};

    const int kiters = K / 64;
    for (int kt = 0; kt < kiters; ++kt) {
        const int off = kt * 64;
        v16c r0, r1;
        if (ASRC == 1) {
#pragma unroll
            for (int c = 0; c < 4; ++c) {
                v4fl f0 = *(const v4fl*)(gA32 + off + c * 4);
                v4fl f1 = *(const v4fl*)(gA32 + off + 16 + c * 4);
#pragma unroll
                for (int e = 0; e < 4; ++e) {
                    float t0 = rintf(f0[e] * qsc);
                    float t1 = rintf(f1[e] * qsc);
                    r0[c * 4 + e] = (i8_t)(int)fminf(127.f, fmaxf(-127.f, t0));
                    r1[c * 4 + e] = (i8_t)(int)fminf(127.f, fmaxf(-127.f, t1));
                }
            }
        } else if (ASRC == 2) {
#pragma unroll
            for (int c = 0; c < 2; ++c) {
                v8h h0 = *(const v8h*)(gAh + off + c * 8);
                v8h h1 = *(const v8h*)(gAh + off + 16 + c * 8);
#pragma unroll
                for (int e = 0; e < 8; ++e) {
                    float t0 = rintf((float)h0[e] * qsc);
                    float t1 = rintf((float)h1[e] * qsc);
                    r0[c * 8 + e] = (i8_t)(int)fminf(127.f, fmaxf(-127.f, t0));
                    r1[c * 8 + e] = (i8_t)(int)fminf(127.f, fmaxf(-127.f, t1));
                }
            }
        }
        __syncthreads();
        gload16(gB0 + off, lB0);
        gload16(gB1 + off, lB1);
        if (ASRC == 0) {
            gload16(gA0 + off, lA0);
            gload16(gA1 + off, lA1);
        } else {
            *(v16c*)qdst = r0;
            *(v16c*)(qdst + 16) = r1;
        }
        __syncthreads();

        v4i af[4], bfr[4];
#pragma unroll
        for (int mi = 0; mi < 4; ++mi)
            af[mi] = *(const v4i*)(As + (wr * 64 + mi * 16 + lrow) * 64 + lq * 16);
#pragma unroll
        for (int nj = 0; nj < 4; ++nj)
            bfr[nj] = *(const v4i*)(Bs + (wc * 64 + nj * 16 + lrow) * 64 + lq * 16);
#pragma unroll
        for (int mi = 0; mi < 4; ++mi)
#pragma unroll
            for (int nj = 0; nj < 4; ++nj)
                acc[mi][nj] = __builtin_amdgcn_mfma_i32_16x16x64_i8(
                    af[mi], bfr[nj], acc[mi][nj], 0, 0, 0);
    }

    const float sw = wscale[0];
#pragma unroll
    for (int mi = 0; mi < 4; ++mi) {
#pragma unroll
        for (int r = 0; r < 4; ++r) {
            const int row = m0 + wr * 64 + mi * 16 + lq * 4 + r;
            const float rs = sw * rowscale[row];
#pragma unroll
            for (int nj = 0; nj < 4; ++nj) {
                const int col = n0 + wc * 64 + nj * 16 + lrow;
                float v = (float)acc[mi][nj][r] * rs;
                if (EPI == 0) {
                    ((float*)Cv)[(size_t)row * N + col] = v;
                } else if (EPI == 1) {
                    v = fmaxf(v, 0.f); v = v * v;
                    ((half_t*)Cv)[(size_t)row * N + col] = (half_t)v;
                } else {
                    v = fmaxf(v, 0.f); v = v * v;
                    ((float*)Cv)[(size_t)row * N + col] = v;
                }
            }
        }
    }
}

extern "C" void kernel_launch(void* const* d_in, const int* in_sizes, int n_in,
                              void* d_out, int out_size, void* d_ws, size_t ws_size,
                              hipStream_t stream) {
    const float* x   = (const float*)d_in[0];   // [T, H] fp32
    const float* wup = (const float*)d_in[1];   // [I, H] fp32
    const float* wdn = (const float*)d_in[2];   // [H, I] fp32

    const int H = 2048;
    const int T = in_sizes[0] / H;              // 16384
    const int I = in_sizes[1] / H;              // 4096
    const long nw = (long)in_sizes[1];          // 8388608
    const float winv = 1.0f / (float)nw;

    char* p = (char*)d_ws;
    float* scales  = (float*)p;
    float* part_up = (float*)(p + 256);
    float* part_dn = (float*)(p + 1280);
    float* a_scale = (float*)(p + 2304);
    float* h_scale = a_scale + T;
    float* h_recip = h_scale + T;
    size_t off = 2304 + (size_t)12 * T;
    off = (off + 255) & ~(size_t)255;
    i8_t* xq  = (i8_t*)(p + off); off += (size_t)T * H;
    off = (off + 255) & ~(size_t)255;
    i8_t* wqu = (i8_t*)(p + off); off += (size_t)I * H;
    off = (off + 255) & ~(size_t)255;
    i8_t* wqd = (i8_t*)(p + off); off += (size_t)H * I;
    off = (off + 255) & ~(size_t)255;
    void* h  = (void*)(p + off);
    i8_t* hq = (i8_t*)(p + off + (size_t)T * I * 4);

    const size_t need_full = off + (size_t)T * I * 5;
    const size_t need_h32  = off + (size_t)T * I * 4;
    const int mode = (ws_size == 0 || need_full <= ws_size) ? 0
                   : (need_h32 <= ws_size ? 1 : 2);
    const bool big_ok = (T % 256 == 0) && (I % 256 == 0) && (H % 256 == 0) &&
                        (H >= 256) && (I >= 256);

    // fused deterministic mean|w| for both matrices, then fixed-order combine
    abssum_partial2<<<512, 256, 0, stream>>>(wup, wdn, nw, part_up, part_dn);
    abssum_final<<<1, 128, 0, stream>>>(part_up, part_dn, scales, winv);

    int wblocks = (int)(nw / 2048);
    wquant2_kernel<<<2 * wblocks, 256, 0, stream>>>(wup, wdn, wqu, wqd, scales, wblocks);

    rowquant_kernel<2048><<<(T + 3) / 4, 256, 0, stream>>>(x, xq, a_scale, T);

    if (mode == 0 && big_ok) {
        gemm_bt8<2><<<dim3(I / 256, T / 256), 512, 0, stream>>>(
            xq, wqu, h, a_scale, scales + 0, T, I, H);
        rowquant_kernel<4096><<<(T + 3) / 4, 256, 0, stream>>>(
            (const float*)h, hq, h_scale, T);
        gemm_bt8<0><<<dim3(H / 256, T / 256), 512, 0, stream>>>(
            hq, wqd, d_out, h_scale, scales + 1, T, H, I);
    } else if (mode == 0) {
        gemm_bt<0, 2><<<dim3(I / 128, T / 128), 256, 0, stream>>>(
            xq, wqu, h, a_scale, nullptr, scales + 0, T, I, H);
        rowquant_kernel<4096><<<(T + 3) / 4, 256, 0, stream>>>(
            (const float*)h, hq, h_scale, T);
        gemm_bt<0, 0><<<dim3(H / 128, T / 128), 256, 0, stream>>>(
            hq, wqd, d_out, h_scale, nullptr, scales + 1, T, H, I);
    } else if (mode == 1) {
        gemm_bt<0, 2><<<dim3(I / 128, T / 128), 256, 0, stream>>>(
            xq, wqu, h, a_scale, nullptr, scales + 0, T, I, H);
        hamax_kernel<float, 2><<<T, 256, 0, stream>>>((const float*)h, h_scale, h_recip);
        gemm_bt<1, 0><<<dim3(H / 128, T / 128), 256, 0, stream>>>(
            h, wqd, d_out, h_scale, h_recip, scales + 1, T, H, I);
    } else {
        gemm_bt<0, 1><<<dim3(I / 128, T / 128), 256, 0, stream>>>(
            xq, wqu, h, a_scale, nullptr, scales + 0, T, I, H);
        hamax_kernel<half_t, 2><<<T, 256, 0, stream>>>((const half_t*)h, h_scale, h_recip);
        gemm_bt<2, 0><<<dim3(H / 128, T / 128), 256, 0, stream>>>(
            h, wqd, d_out, h_scale, h_recip, scales + 1, T, H, I);
    }
}